// Round 11
// baseline (330.062 us; speedup 1.0000x reference)
//
#include <hip/hip_runtime.h>
#include <hip/hip_fp16.h>

#define D 128
#define NBK 512            // max buckets
#define CAP 4544           // slack bucket capacity: mean 4092 + ~7 sigma
#define PART_CHUNK 3072    // R9-proven (R10's 1536 regressed)

using f32x4  = __attribute__((ext_vector_type(4))) float;
using half8  = __attribute__((ext_vector_type(8))) _Float16;
using short8 = __attribute__((ext_vector_type(8))) short;

#define AS1(p) ((const __attribute__((address_space(1))) void*)(p))
#define AS3(p) ((__attribute__((address_space(3))) void*)(p))

// v_fma_mix_f32: acc += (float)(f16 half of dw) * 1.0f  — one VALU op per element
#define FMA_MIX_LO(acc, dw, one) \
    asm("v_fma_mix_f32 %0, %1, %2, %0 op_sel:[0,0,0] op_sel_hi:[1,0,0]" \
        : "+v"(acc) : "v"(dw), "v"(one))
#define FMA_MIX_HI(acc, dw, one) \
    asm("v_fma_mix_f32 %0, %1, %2, %0 op_sel:[1,0,0] op_sel_hi:[1,0,0]" \
        : "+v"(acc) : "v"(dw), "v"(one))

// ------------------------------------------------ prep (R9-proven): W split + x->fp16
//  blocks [0, 256)   : W1/W2 -> f16 hi/lo planes; block 0 zeroes both pad rows
//  blocks [256, ...) : x fp32 -> fp16
// Wg layout: (((kc*2 + plane)*4 + q)*128 + col)*8 + j ; k = kc*32+q*8+j
__global__ void prep_k(const float* __restrict__ x, __half* __restrict__ y, int n4,
                       const float* __restrict__ W1s, const float* __restrict__ W1n,
                       const float* __restrict__ W2s, const float* __restrict__ W2n,
                       unsigned short* __restrict__ Wg1, unsigned short* __restrict__ Wg2,
                       float* __restrict__ xpad, float* __restrict__ hpad) {
    int b = blockIdx.x;
    int t = threadIdx.x;
    if (b < 256) {                 // weight hi/lo split
        if (b == 0 && t < 64) { xpad[t] = 0.f; hpad[t] = 0.f; }  // zero-gather rows
        int sel = b >> 7;          // 0: W1, 1: W2
        int lb  = b & 127;
        const float* Ws = sel ? W2s : W1s;
        const float* Wn = sel ? W2n : W1n;
        unsigned short* Wg = sel ? Wg2 : Wg1;
        int idx = lb * 256 + t;    // 0 .. 32767
        int col = idx >> 8;
        int k   = idx & 255;
        float v = (k < 128) ? Ws[k * D + col] : Wn[(k - 128) * D + col];
        _Float16 hv = (_Float16)v;
        _Float16 lv = (_Float16)(v - (float)hv);
        int kc = k >> 5, q = (k >> 3) & 3, j = k & 7;
        Wg[(((kc * 2 + 0) * 4 + q) * 128 + col) * 8 + j] = *(unsigned short*)&hv;
        Wg[(((kc * 2 + 1) * 4 + q) * 128 + col) * 8 + j] = *(unsigned short*)&lv;
        return;
    }
    int i = (b - 256) * 256 + t;
    if (i < n4) {
        float4 v = *(const float4*)(x + (size_t)i * 4);
        __half2 h0 = __floats2half2_rn(v.x, v.y);
        __half2 h1 = __floats2half2_rn(v.z, v.w);
        __half2* o = (__half2*)(y + (size_t)i * 4);
        o[0] = h0; o[1] = h1;
    }
}

// ------------------------------------------------ partition (R9-proven, unchanged)
__global__ __launch_bounds__(256)
void partition_k(const int* __restrict__ src, const int* __restrict__ dst,
                 int* __restrict__ cursor, unsigned* __restrict__ pairs,
                 int E, int nb, int wmax) {
    __shared__ int hist[NBK];
    __shared__ int gbase[NBK];
    int t = threadIdx.x;
    int e0 = blockIdx.x * PART_CHUNK;
    int e1 = min(E, e0 + PART_CHUNK);
    int e1a = e0 + ((e1 - e0) & ~3);
    for (int b = t; b < nb; b += 256) hist[b] = 0;
    __syncthreads();
    for (int i = e0 + t * 4; i + 3 < e1; i += 1024) {
        int4 d4 = *(const int4*)(dst + i);
        atomicAdd(&hist[d4.x >> 8], 1);
        atomicAdd(&hist[d4.y >> 8], 1);
        atomicAdd(&hist[d4.z >> 8], 1);
        atomicAdd(&hist[d4.w >> 8], 1);
    }
    for (int i = e1a + t; i < e1; i += 256)
        atomicAdd(&hist[dst[i] >> 8], 1);
    __syncthreads();
    for (int b = t; b < nb; b += 256) {
        int c = hist[b];
        int g = b * CAP;
        if (c) g += atomicAdd(&cursor[b], c);
        gbase[b] = g;
        hist[b] = 0;               // reuse as local cursor
    }
    __syncthreads();
    for (int i = e0 + t * 4; i + 3 < e1; i += 1024) {
        int4 d4 = *(const int4*)(dst + i);
        int4 s4 = *(const int4*)(src + i);
        int b0 = d4.x >> 8, b1 = d4.y >> 8, b2 = d4.z >> 8, b3 = d4.w >> 8;
        int r0 = atomicAdd(&hist[b0], 1);
        int r1 = atomicAdd(&hist[b1], 1);
        int r2 = atomicAdd(&hist[b2], 1);
        int r3 = atomicAdd(&hist[b3], 1);
        pairs[min(gbase[b0] + r0, wmax)] = ((unsigned)(d4.x & 255) << 17) | (unsigned)s4.x;
        pairs[min(gbase[b1] + r1, wmax)] = ((unsigned)(d4.y & 255) << 17) | (unsigned)s4.y;
        pairs[min(gbase[b2] + r2, wmax)] = ((unsigned)(d4.z & 255) << 17) | (unsigned)s4.z;
        pairs[min(gbase[b3] + r3, wmax)] = ((unsigned)(d4.w & 255) << 17) | (unsigned)s4.w;
    }
    for (int i = e1a + t; i < e1; i += 256) {
        int dd = dst[i];
        int bb = dd >> 8;
        int r = atomicAdd(&hist[bb], 1);
        pairs[min(gbase[bb] + r, wmax)] = ((unsigned)(dd & 255) << 17) | (unsigned)src[i];
    }
}

// ------------------------------------------------ fused sort + aggregate + GEMM
// One block per 256-node bucket, 1024 thr = 16 waves, ~109KB LDS (1 block/CU).
// layer1: sort pairs (reg-staged, LDS int atomics), writeback sorted + offcnt
//         (packed LOCAL soff<<9|cnt), gather means into agg_lds, then GEMM
//         h = relu(x@Ws + mean@Wn + b) -> hout fp16 (separate buffer - other
//         blocks still gather x, in-place would race).
// layer0: reload sorted srcs + offcnt, gather, GEMM -> fout fp32.
// GEMM is row-local to the bucket: block b's means are exactly GEMM rows
// [b*256, b*256+256), A1 fragments come straight from agg_lds (+16B row pad
// -> conflict-free ds_read_b128), saving the 51MB agg roundtrip per layer.
__global__ __launch_bounds__(1024)
void agg_gemm_k(const __half* __restrict__ xin, unsigned* pairs,
                const int* __restrict__ cursor, unsigned* __restrict__ offcnt,
                const unsigned short* __restrict__ Wg,
                const float* __restrict__ bias,
                __half* __restrict__ hout, float* __restrict__ fout,
                int n, int layer1) {
    __shared__ int srcs[CAP];
    __shared__ __align__(16) __half agg_lds[256][D + 8];   // +16B pad: spread banks
    __shared__ __align__(16) unsigned short lds_b[8192];   // 16 KB W-stage
    __shared__ int sh[256];
    __shared__ int hist[256];
    __shared__ int curs[256];
    __shared__ int soff[256];
    __shared__ int scnt[256];
    int t = threadIdx.x;
    int b = blockIdx.x;
    int e0 = b * CAP;
    int cnt = min(cursor[b], CAP);
    int node0 = b << 8;
    if (layer1) {
        // ---- counting sort (register-staged single read; R10-neutral, keeps 1 pass)
        if (t < 256) hist[t] = 0;
        __syncthreads();
        unsigned pr[5];
        #pragma unroll
        for (int j = 0; j < 5; ++j) {
            int idx = j * 1024 + t;
            pr[j] = (idx < cnt) ? pairs[e0 + idx] : 0xFFFFFFFFu;
        }
        #pragma unroll
        for (int j = 0; j < 5; ++j)
            if (pr[j] != 0xFFFFFFFFu) atomicAdd(&hist[pr[j] >> 17], 1);
        __syncthreads();
        int c = 0;
        if (t < 256) { c = hist[t]; sh[t] = c; }
        __syncthreads();
        for (int off = 1; off < 256; off <<= 1) {
            int v = 0;
            if (t >= off && t < 256) v = sh[t - off];
            __syncthreads();
            if (t >= off && t < 256) sh[t] += v;
            __syncthreads();
        }
        if (t < 256) {
            int excl = sh[t] - c;
            curs[t] = excl;
            soff[t] = excl;
            scnt[t] = c;
            int node = node0 + t;
            if (node < n)
                offcnt[node] = ((unsigned)excl << 9) | (unsigned)min(c, 511);
        }
        __syncthreads();
        #pragma unroll
        for (int j = 0; j < 5; ++j)
            if (pr[j] != 0xFFFFFFFFu) {
                int pos = atomicAdd(&curs[pr[j] >> 17], 1);
                srcs[min(pos, CAP - 1)] = (int)(pr[j] & 0x1FFFFu);
            }
        __syncthreads();
        for (int i = t; i < cnt; i += 1024)       // sorted list for layer 2
            pairs[e0 + i] = (unsigned)srcs[i];
    } else {
        // ---- reload sorted srcs + per-node offsets
        for (int i = t; i < cnt; i += 1024)
            srcs[i] = (int)pairs[e0 + i];
        if (t < 256) {
            int node = node0 + t;
            unsigned pc = (node < n) ? offcnt[node] : 0u;
            soff[t] = (int)(pc >> 9);
            scnt[t] = (int)(pc & 511u);
        }
        __syncthreads();
    }
    // ---- gather phase: wave wv handles nodes wv, wv+16, ...; means -> agg_lds
    int lane = t & 63, wv = t >> 6;
    int sg = lane >> 4, sub = lane & 15;
    float one = 1.0f;
    for (int nl = wv; nl < 256; nl += 16) {
        int node = node0 + nl;
        if (node >= n) break;                 // wave-uniform
        int lstart = soff[nl];
        int cnt2 = scnt[nl];
        float acc[8] = {0.f, 0.f, 0.f, 0.f, 0.f, 0.f, 0.f, 0.f};
        for (int base = 0; base < cnt2; base += 64) {
            int valid = min(64, cnt2 - base);
            int s = (lane < valid) ? srcs[lstart + base + lane] : n;  // n = zero row
            for (int k0 = 0; k0 < valid; k0 += 16) {
                float4 raw[4];
                #pragma unroll
                for (int u = 0; u < 4; ++u) {
                    int row = __shfl(s, (k0 + 4 * u + sg) & 63);
                    raw[u] = *(const float4*)(xin + (size_t)row * D + sub * 8);
                }
                #pragma unroll
                for (int u = 0; u < 4; ++u) {
                    const unsigned* dw = (const unsigned*)&raw[u];
                    #pragma unroll
                    for (int j = 0; j < 4; ++j) {
                        FMA_MIX_LO(acc[2 * j],     dw[j], one);
                        FMA_MIX_HI(acc[2 * j + 1], dw[j], one);
                    }
                }
            }
        }
        #pragma unroll
        for (int j = 0; j < 8; ++j) {
            acc[j] += __shfl(acc[j], lane ^ 16);
            acc[j] += __shfl(acc[j], lane ^ 32);
        }
        if (sg == 0) {
            float inv = 1.0f / fmaxf((float)cnt2, 1.0f);
            union { __half2 h2[4]; short8 s8; } u8;
            #pragma unroll
            for (int j = 0; j < 4; ++j)
                u8.h2[j] = __floats2half2_rn(acc[2 * j] * inv, acc[2 * j + 1] * inv);
            *(short8*)(&agg_lds[nl][sub * 8]) = u8.s8;
        }
    }
    __syncthreads();
    // ---- GEMM phase: 16 waves x 16 rows; A0 global, A1 from agg_lds, B staged
    int m = lane & 15, q = lane >> 4;
    int rowl = wv * 16 + m;                  // A row (local) this lane loads
    int rowg = node0 + rowl;
    f32x4 acc2[8];
    #pragma unroll
    for (int ct = 0; ct < 8; ++ct) acc2[ct] = (f32x4){0.f, 0.f, 0.f, 0.f};
    for (int kc = 0; kc < 8; ++kc) {
        const unsigned short* gk = Wg + (size_t)kc * 8192;
        __builtin_amdgcn_global_load_lds(AS1(gk + t * 8), AS3(lds_b + t * 8), 16, 0, 0);
        int ka = (kc & 3) * 32;
        half8 a;
        if (kc < 4) {
            a = (half8){0, 0, 0, 0, 0, 0, 0, 0};
            if (rowg < n)
                a = *(const half8*)((const _Float16*)xin + (size_t)rowg * D + ka + q * 8);
        } else {
            a = *(const half8*)(&agg_lds[rowl][ka + q * 8]);  // rows>=n garbage: contained, write-guarded
        }
        __syncthreads();     // drains global_load_lds + barrier
        #pragma unroll
        for (int ct = 0; ct < 8; ++ct) {
            half8 bh = *(const half8*)&lds_b[(size_t)(q * 128 + ct * 16 + m) * 8];
            half8 bl = *(const half8*)&lds_b[(size_t)((4 + q) * 128 + ct * 16 + m) * 8];
            acc2[ct] = __builtin_amdgcn_mfma_f32_16x16x32_f16(a, bh, acc2[ct], 0, 0, 0);
            acc2[ct] = __builtin_amdgcn_mfma_f32_16x16x32_f16(a, bl, acc2[ct], 0, 0, 0);
        }
        __syncthreads();     // LDS reads done before next stage overwrites
    }
    #pragma unroll
    for (int ct = 0; ct < 8; ++ct) {
        int col = ct * 16 + m;
        float bb = bias[col];
        #pragma unroll
        for (int r = 0; r < 4; ++r) {
            int row = node0 + wv * 16 + q * 4 + r;
            if (row < n) {
                float v = acc2[ct][r] + bb;
                if (layer1) {
                    v = fmaxf(v, 0.f);
                    hout[(size_t)row * D + col] = __float2half(v);
                } else {
                    fout[(size_t)row * D + col] = v;
                }
            }
        }
    }
}

// ------------------------------------------------------------------- launch
extern "C" void kernel_launch(void* const* d_in, const int* in_sizes, int n_in,
                              void* d_out, int out_size, void* d_ws, size_t ws_size,
                              hipStream_t stream) {
    const float* in_feat = (const float*)d_in[0];
    const float* W1s     = (const float*)d_in[1];
    const float* W1n     = (const float*)d_in[2];
    const float* b1      = (const float*)d_in[3];
    const float* W2s     = (const float*)d_in[4];
    const float* W2n     = (const float*)d_in[5];
    const float* b2      = (const float*)d_in[6];
    const int*   src     = (const int*)d_in[7];
    const int*   dst     = (const int*)d_in[8];

    const int N  = in_sizes[0] / D;
    const int E  = in_sizes[7];
    const int NB = (N + 255) >> 8;     // 256-node buckets (391)

    // workspace layout (~59.0 MB, R9-proven footprint)
    char* base = (char*)d_ws;
    size_t off = 0;
    __half* h16  = (__half*)(base + off); off += ((size_t)N * D + D) * 2;   // layer-1 output (+ zero pad row)
    __half* xh16 = (__half*)(base + off); off += ((size_t)N * D + D) * 2;   // x fp16 (+ zero pad row)
    unsigned* pairs = (unsigned*)(base + off); off += (size_t)NB * CAP * 4; // slack buckets -> sorted edges
    unsigned* offcnt = (unsigned*)(base + off); off += (size_t)N * 4;       // packed local soff<<9|cnt
    unsigned short* Wg1 = (unsigned short*)(base + off); off += 65536 * 2;
    unsigned short* Wg2 = (unsigned short*)(base + off); off += 65536 * 2;
    int* cursor = (int*)(base + off); off += NBK * 4;

    float* xpad = (float*)(xh16 + (size_t)N * D);   // zero row at index N (x)
    float* hpad = (float*)(h16  + (size_t)N * D);   // zero row at index N (h)

    const int n4 = (N * D) / 4;
    const int xb = (n4 + 255) / 256;
    const int pblk = (E + PART_CHUNK - 1) / PART_CHUNK;   // 521

    hipMemsetAsync(cursor, 0, NBK * 4, stream);

    // prep: W split + x->fp16 + zero pad rows
    hipLaunchKernelGGL(prep_k, dim3(256 + xb), dim3(256), 0, stream,
                       in_feat, xh16, n4, W1s, W1n, W2s, W2n, Wg1, Wg2, xpad, hpad);

    // slack-bucket partition (R9-proven)
    hipLaunchKernelGGL(partition_k, dim3(pblk), dim3(256), 0, stream,
                       src, dst, cursor, pairs, E, NB, NB * CAP - 1);

    // layer 1: sort + gather(x16) + GEMM1 -> h16 (fused; emits sorted pairs + offcnt)
    hipLaunchKernelGGL(agg_gemm_k, dim3(NB), dim3(1024), 0, stream,
                       xh16, pairs, cursor, offcnt, Wg1, b1,
                       h16, (float*)nullptr, N, 1);

    // layer 2: gather(h16) + GEMM2 -> d_out fp32 (fused)
    hipLaunchKernelGGL(agg_gemm_k, dim3(NB), dim3(1024), 0, stream,
                       h16, pairs, cursor, offcnt, Wg2, b2,
                       (__half*)nullptr, (float*)d_out, N, 0);
}